// Round 7
// baseline (2809.007 us; speedup 1.0000x reference)
//
#include <hip/hip_runtime.h>
#include <math.h>

namespace {

constexpr int T_STEPS = 512;

typedef _Float16 h8v __attribute__((ext_vector_type(8)));
typedef _Float16 h4v __attribute__((ext_vector_type(4)));
typedef float    f4v __attribute__((ext_vector_type(4)));

__device__ __forceinline__ float sigf(float v) { return 1.0f / (1.0f + __expf(-v)); }
__device__ __forceinline__ float tanh_(float v) { return 2.0f / (1.0f + __expf(-2.0f * v)) - 1.0f; }

// Pack weights into MFMA B-fragment load order, fp16. Tile n (0..31) covers
// gates [16n, 16n+16). Frag elem [l][j]: gate = 16n + (l&15),
// k = 32*ks + 8*(l>>4) + j.
// PA frag (n*6+ks): ks 0-1 = Wih0 (K=64), ks 2-5 = Whh0 (K=128).
// PB frag (n*8+ks): ks 0-3 = Wih1, ks 4-7 = Whh1.
__global__ void pack_w(const float* __restrict__ Wih0, const float* __restrict__ Whh0,
                       const float* __restrict__ Wih1, const float* __restrict__ Whh1,
                       _Float16* __restrict__ PA, _Float16* __restrict__ PB) {
  int idx = blockIdx.x * 256 + threadIdx.x;
  if (idx < 98304) {
    int j = idx & 7, l = (idx >> 3) & 63;
    int f = idx >> 9;
    int ks = f % 6, n = f / 6;
    int gate = 16 * n + (l & 15);
    int k = 32 * ks + ((l >> 4) << 3) + j;
    float v = (k < 64) ? Wih0[gate * 64 + k] : Whh0[gate * 128 + (k - 64)];
    PA[idx] = (_Float16)v;
  } else if (idx < 229376) {
    int i = idx - 98304;
    int j = i & 7, l = (i >> 3) & 63;
    int f = i >> 9;
    int ks = f & 7, n = f >> 3;
    int gate = 16 * n + (l & 15);
    int k = 32 * ks + ((l >> 4) << 3) + j;
    float v = (k < 128) ? Wih1[gate * 128 + k] : Whh1[gate * 128 + (k - 128)];
    PB[i] = (_Float16)v;
  }
}

// 64 blocks x 256 threads (4 waves), 1 wave/SIMD (waves_per_eu(1,1) => 512-reg
// budget/wave). Wave w owns units [32w, 32w+32) x all 4 gate types: q = 2t+s
// (t = gate type i/f/g/o, s = unit half), tile n = 8t + 2w + s. Per-wave
// weights register-resident: Whh0 (W0h) + Wih1 (W1a) + Whh1 (W1b) = 96 frags
// = 384 VGPRs; Wih0 (x-side) in LDS. Fused pipeline: iter j = layer0 step j
// + layer1 step j-1 (independent), one barrier/iter. Cell state c fp32 in
// registers; update is lane-local (lane lo holds units 32w+lo, 32w+16+lo for
// rows hi*4+r).
__global__ __attribute__((amdgpu_waves_per_eu(1, 1))) __launch_bounds__(256)
void lstm_block(
    const float* __restrict__ x,
    const _Float16* __restrict__ PA, const _Float16* __restrict__ PB,
    const float* __restrict__ b0, const float* __restrict__ b1,
    const float* __restrict__ Wout, const float* __restrict__ bout,
    float* __restrict__ out) {
  extern __shared__ char smem[];
  h8v* wx = (h8v*)smem;  // Wih0 frags [32 n][2 ks][64 l] = 64 KB
  _Float16(*h0t)[4][64][8] = (_Float16(*)[4][64][8])(smem + 65536);  // [2][4][64][8] 8 KB
  _Float16(*h1t)[4][64][8] = (_Float16(*)[4][64][8])(smem + 73728);  // 8 KB
  _Float16(*xt)[2][64][8]  = (_Float16(*)[2][64][8])(smem + 81920);  // [2][2][64][8] 4 KB

  const int tid = threadIdx.x;
  const int g = blockIdx.x;
  const int w = tid >> 6, l = tid & 63;
  const int lo = l & 15, hi = l >> 4;

  const h8v* PAv = (const h8v*)PA;
  const h8v* PBv = (const h8v*)PB;

  // ---- register-resident weights: q = 2t+s -> tile n = 8t + 2w + s ----
  h8v W0h[8][4], W1a[8][4], W1b[8][4];
#pragma unroll
  for (int t = 0; t < 4; ++t)
#pragma unroll
    for (int s = 0; s < 2; ++s) {
      int q = 2 * t + s, n = 8 * t + 2 * w + s;
#pragma unroll
      for (int ks = 0; ks < 4; ++ks) {
        W0h[q][ks] = PAv[(n * 6 + 2 + ks) * 64 + l];
        W1a[q][ks] = PBv[(n * 8 + ks) * 64 + l];
        W1b[q][ks] = PBv[(n * 8 + 4 + ks) * 64 + l];
      }
    }
#pragma unroll
  for (int q = 0; q < 8; ++q)
#pragma unroll
    for (int ks = 0; ks < 4; ++ks) {
      asm volatile("" : "+v"(W0h[q][ks]));
      asm volatile("" : "+v"(W1a[q][ks]));
      asm volatile("" : "+v"(W1b[q][ks]));
    }
  float bA[8], bB[8];
#pragma unroll
  for (int t = 0; t < 4; ++t)
#pragma unroll
    for (int s = 0; s < 2; ++s) {
      int q = 2 * t + s, gidx = 128 * t + 32 * w + 16 * s + lo;
      bA[q] = b0[gidx];
      bB[q] = b1[gidx];
    }
  float c0[2][4] = {{0.f, 0.f, 0.f, 0.f}, {0.f, 0.f, 0.f, 0.f}};
  float c1[2][4] = {{0.f, 0.f, 0.f, 0.f}, {0.f, 0.f, 0.f, 0.f}};

  // ---- stage Wih0 frags into LDS ----
  for (int i = tid; i < 4096; i += 256) {
    int n = i >> 7, ks = (i >> 6) & 1, ll = i & 63;
    wx[i] = PAv[(n * 6 + ks) * 64 + ll];
  }
  // ---- zero h tiles, stage x(0) ----
  {
    unsigned int* z0 = (unsigned int*)h0t;
    unsigned int* z1 = (unsigned int*)h1t;
    for (int i = tid; i < 2048; i += 256) { z0[i] = 0u; z1[i] = 0u; }
    int row = tid >> 4, kk = (tid & 15) << 2;
    float4 v = *(const float4*)(x + (((long)(g * 16 + row)) * T_STEPS) * 64 + kk);
    h4v pv;
    pv.x = (_Float16)v.x; pv.y = (_Float16)v.y;
    pv.z = (_Float16)v.z; pv.w = (_Float16)v.w;
    *(h4v*)&xt[0][kk >> 5][(((kk >> 3) & 3) * 16) + row][kk & 7] = pv;
  }
  __syncthreads();

  // Fused: iter j = A(j) [layer0 step j] + B(j-1) [layer1 step j-1].
  for (int j = 0; j <= T_STEPS; ++j) {
    const int p = j & 1;
    h8v h00 = *(const h8v*)&h0t[p][0][l][0];
    h8v h01 = *(const h8v*)&h0t[p][1][l][0];
    h8v h02 = *(const h8v*)&h0t[p][2][l][0];
    h8v h03 = *(const h8v*)&h0t[p][3][l][0];

    if (j < T_STEPS) {
      h8v ax0 = *(const h8v*)&xt[p][0][l][0];
      h8v ax1 = *(const h8v*)&xt[p][1][l][0];
#pragma unroll
      for (int s = 0; s < 2; ++s) {
        f4v acc[4];
#pragma unroll
        for (int t = 0; t < 4; ++t) {
          int q = 2 * t + s, n = 8 * t + 2 * w + s;
          const h8v* wxp = wx + n * 128 + l;
          f4v z = {bA[q], bA[q], bA[q], bA[q]};
          z = __builtin_amdgcn_mfma_f32_16x16x32_f16(ax0, wxp[0], z, 0, 0, 0);
          z = __builtin_amdgcn_mfma_f32_16x16x32_f16(ax1, wxp[64], z, 0, 0, 0);
          z = __builtin_amdgcn_mfma_f32_16x16x32_f16(h00, W0h[q][0], z, 0, 0, 0);
          z = __builtin_amdgcn_mfma_f32_16x16x32_f16(h01, W0h[q][1], z, 0, 0, 0);
          z = __builtin_amdgcn_mfma_f32_16x16x32_f16(h02, W0h[q][2], z, 0, 0, 0);
          z = __builtin_amdgcn_mfma_f32_16x16x32_f16(h03, W0h[q][3], z, 0, 0, 0);
          acc[t] = z;
        }
#pragma unroll
        for (int r = 0; r < 4; ++r) {
          float cn = sigf(acc[1][r]) * c0[s][r] + sigf(acc[0][r]) * tanh_(acc[2][r]);
          c0[s][r] = cn;
          float hv = sigf(acc[3][r]) * tanh_(cn);
          h0t[p ^ 1][w][(2 * s + (lo >> 3)) * 16 + hi * 4 + r][lo & 7] = (_Float16)hv;
        }
      }
      if (j + 1 < T_STEPS) {  // stage x(j+1) -> xt[p^1]
        int row = tid >> 4, kk = (tid & 15) << 2;
        float4 v = *(const float4*)(x + (((long)(g * 16 + row)) * T_STEPS + (j + 1)) * 64 + kk);
        h4v pv;
        pv.x = (_Float16)v.x; pv.y = (_Float16)v.y;
        pv.z = (_Float16)v.z; pv.w = (_Float16)v.w;
        *(h4v*)&xt[p ^ 1][kk >> 5][(((kk >> 3) & 3) * 16) + row][kk & 7] = pv;
      }
    }

    if (j >= 1) {
      h8v f10 = *(const h8v*)&h1t[p][0][l][0];
      h8v f11 = *(const h8v*)&h1t[p][1][l][0];
      h8v f12 = *(const h8v*)&h1t[p][2][l][0];
      h8v f13 = *(const h8v*)&h1t[p][3][l][0];
#pragma unroll
      for (int s = 0; s < 2; ++s) {
        f4v acc[4];
#pragma unroll
        for (int t = 0; t < 4; ++t) {
          int q = 2 * t + s;
          f4v z = {bB[q], bB[q], bB[q], bB[q]};
          z = __builtin_amdgcn_mfma_f32_16x16x32_f16(h00, W1a[q][0], z, 0, 0, 0);
          z = __builtin_amdgcn_mfma_f32_16x16x32_f16(h01, W1a[q][1], z, 0, 0, 0);
          z = __builtin_amdgcn_mfma_f32_16x16x32_f16(h02, W1a[q][2], z, 0, 0, 0);
          z = __builtin_amdgcn_mfma_f32_16x16x32_f16(h03, W1a[q][3], z, 0, 0, 0);
          z = __builtin_amdgcn_mfma_f32_16x16x32_f16(f10, W1b[q][0], z, 0, 0, 0);
          z = __builtin_amdgcn_mfma_f32_16x16x32_f16(f11, W1b[q][1], z, 0, 0, 0);
          z = __builtin_amdgcn_mfma_f32_16x16x32_f16(f12, W1b[q][2], z, 0, 0, 0);
          z = __builtin_amdgcn_mfma_f32_16x16x32_f16(f13, W1b[q][3], z, 0, 0, 0);
          acc[t] = z;
        }
#pragma unroll
        for (int r = 0; r < 4; ++r) {
          float cn = sigf(acc[1][r]) * c1[s][r] + sigf(acc[0][r]) * tanh_(acc[2][r]);
          c1[s][r] = cn;
          float hv = sigf(acc[3][r]) * tanh_(cn);
          h1t[p ^ 1][w][(2 * s + (lo >> 3)) * 16 + hi * 4 + r][lo & 7] = (_Float16)hv;
        }
      }
    }
    __syncthreads();
  }

  // ---- output projection: y = h1(T-1) . Wout^T + bout ; h1(T-1) in h1t[1] ----
  if (tid < 16) {
    float acc = bout[0];
#pragma unroll 4
    for (int u = 0; u < 128; ++u) {
      float hval = (float)h1t[1][u >> 5][(((u >> 3) & 3) * 16) + tid][u & 7];
      acc = fmaf(hval, Wout[u], acc);
    }
    out[g * 16 + tid] = acc;
  }
}

}  // namespace

extern "C" void kernel_launch(void* const* d_in, const int* in_sizes, int n_in,
                              void* d_out, int out_size, void* d_ws, size_t ws_size,
                              hipStream_t stream) {
  const float* x    = (const float*)d_in[0];
  const float* Wih0 = (const float*)d_in[1];
  const float* Whh0 = (const float*)d_in[2];
  const float* b0   = (const float*)d_in[3];
  const float* Wih1 = (const float*)d_in[4];
  const float* Whh1 = (const float*)d_in[5];
  const float* b1   = (const float*)d_in[6];
  const float* Wout = (const float*)d_in[7];
  const float* bout = (const float*)d_in[8];
  float* out = (float*)d_out;

  char* ws = (char*)d_ws;
  _Float16* PA = (_Float16*)ws;             // 196608 B
  _Float16* PB = (_Float16*)(ws + 196608);  // 262144 B

  const int lds_bytes = 65536 + 8192 + 8192 + 4096;  // 86016
  hipFuncSetAttribute((const void*)lstm_block,
                      hipFuncAttributeMaxDynamicSharedMemorySize, lds_bytes);

  pack_w<<<dim3(896), dim3(256), 0, stream>>>(Wih0, Whh0, Wih1, Whh1, PA, PB);
  lstm_block<<<dim3(64), dim3(256), lds_bytes, stream>>>(
      x, PA, PB, b0, b1, Wout, bout, out);
}

// Round 8
// 2007.906 us; speedup vs baseline: 1.3990x; 1.3990x over previous
//
#include <hip/hip_runtime.h>
#include <math.h>

namespace {

constexpr int T_STEPS = 512;

typedef _Float16 h8v __attribute__((ext_vector_type(8)));
typedef _Float16 h2v __attribute__((ext_vector_type(2)));
typedef float    f4v __attribute__((ext_vector_type(4)));

__device__ __forceinline__ float sigf(float v) { return 1.0f / (1.0f + __expf(-v)); }
__device__ __forceinline__ float tanh_(float v) { return 2.0f / (1.0f + __expf(-2.0f * v)) - 1.0f; }

// Pack weights into MFMA B-fragment load order, fp16 (layout HW-verified R3+).
// Tile n (0..31) covers gates [16n,16n+16). Frag elem [l][j]: gate = 16n+(l&15),
// k = 32*ks + 8*(l>>4) + j.
// PA frag (n*6+ks): ks 0-1 = Wih0 (K=64), ks 2-5 = Whh0.
// PB frag (n*8+ks): ks 0-3 = Wih1, ks 4-7 = Whh1.
__global__ void pack_w(const float* __restrict__ Wih0, const float* __restrict__ Whh0,
                       const float* __restrict__ Wih1, const float* __restrict__ Whh1,
                       _Float16* __restrict__ PA, _Float16* __restrict__ PB) {
  int idx = blockIdx.x * 256 + threadIdx.x;
  if (idx < 98304) {
    int j = idx & 7, l = (idx >> 3) & 63;
    int f = idx >> 9;
    int ks = f % 6, n = f / 6;
    int gate = 16 * n + (l & 15);
    int k = 32 * ks + ((l >> 4) << 3) + j;
    float v = (k < 64) ? Wih0[gate * 64 + k] : Whh0[gate * 128 + (k - 64)];
    PA[idx] = (_Float16)v;
  } else if (idx < 229376) {
    int i = idx - 98304;
    int j = i & 7, l = (i >> 3) & 63;
    int f = i >> 9;
    int ks = f & 7, n = f >> 3;
    int gate = 16 * n + (l & 15);
    int k = 32 * ks + ((l >> 4) << 3) + j;
    float v = (k < 128) ? Wih1[gate * 128 + k] : Whh1[gate * 128 + (k - 128)];
    PB[i] = (_Float16)v;
  }
}

// 64 blocks x 1024 threads (16 waves, 4/SIMD). LAYER-SPLIT waves: 0-7 = layer0,
// 8-15 = layer1 (fused pipeline A(j) || B(j-1), independent, 1 barrier/iter).
// Wave w of its group owns units [16w,16w+16) x 4 gate types. Weight placement
// (sized to the hard 128-reg/wave @ 4 waves/SIMD budget):
//   registers: L0-wave Whh0 (16 frags), L1-wave Wih1 (16 frags)  [anchored]
//   LDS (148 KB total): Wih0 (64 KB) + Whh1 k-slices 0-1 (64 KB) + h/x tiles
//   L2-stream: Whh1 k-slices 2-3, re-loaded per step via global (uniform addr,
//              shared across all blocks -> L2-hot; LICM defeated via anchor)
// Cell state c fp32 in registers; lane-local update (no cross-lane exchange).
__global__ __launch_bounds__(1024) void lstm_block(
    const float* __restrict__ x,
    const _Float16* __restrict__ PA, const _Float16* __restrict__ PB,
    const float* __restrict__ b0, const float* __restrict__ b1,
    const float* __restrict__ Wout, const float* __restrict__ bout,
    float* __restrict__ out) {
  extern __shared__ char smem[];
  h8v* whl = (h8v*)smem;             // Whh1 ks4 0-1: [32 n][2][64 l] = 64 KB
  h8v* wxl = (h8v*)(smem + 65536);   // Wih0 ks 0-1:  [32 n][2][64 l] = 64 KB
  _Float16(*h0t)[4][64][8] = (_Float16(*)[4][64][8])(smem + 131072);  // 8 KB
  _Float16(*h1t)[4][64][8] = (_Float16(*)[4][64][8])(smem + 139264);  // 8 KB
  _Float16(*xt)[2][64][8]  = (_Float16(*)[2][64][8])(smem + 147456);  // 4 KB

  const int tid = threadIdx.x;
  const int g = blockIdx.x;
  const int wv = tid >> 6, l = tid & 63;
  const int lo = l & 15, hi = l >> 4;
  const bool isL0 = (wv < 8);
  const int w = isL0 ? wv : (wv - 8);

  const h8v* PAv = (const h8v*)PA;
  const h8v* PBv = (const h8v*)PB;

  // ---- stage LDS-resident weight pieces ----
  for (int i = tid; i < 4096; i += 1024) {
    int n = i >> 7, ks = (i >> 6) & 1, ll = i & 63;
    whl[i] = PBv[(n * 8 + 4 + ks) * 64 + ll];  // Whh1 ks4 0,1
    wxl[i] = PAv[(n * 6 + ks) * 64 + ll];      // Wih0 ks 0,1
  }

  // ---- per-wave register weights: L0 -> Whh0, L1 -> Wih1 (64 regs) ----
  h8v Wr[4][4];
#pragma unroll
  for (int t = 0; t < 4; ++t)
#pragma unroll
    for (int ks = 0; ks < 4; ++ks) {
      int n = 8 * t + w;
      Wr[t][ks] = isL0 ? PAv[(n * 6 + 2 + ks) * 64 + l]
                       : PBv[(n * 8 + ks) * 64 + l];
    }
#pragma unroll
  for (int t = 0; t < 4; ++t)
#pragma unroll
    for (int ks = 0; ks < 4; ++ks) asm volatile("" : "+v"(Wr[t][ks]));

  float br[4], cst[4] = {0.f, 0.f, 0.f, 0.f};
#pragma unroll
  for (int t = 0; t < 4; ++t) {
    int gidx = 128 * t + 16 * w + lo;
    br[t] = isL0 ? b0[gidx] : b1[gidx];
  }

  // ---- zero h tiles, stage x(0) ----
  {
    unsigned int* z0 = (unsigned int*)h0t;
    unsigned int* z1 = (unsigned int*)h1t;
    for (int i = tid; i < 2048; i += 1024) { z0[i] = 0u; z1[i] = 0u; }
    if (tid < 512) {
      int row = tid >> 5, kk = (tid & 31) << 1;
      float2 v = *(const float2*)(x + (((long)(g * 16 + row)) * T_STEPS) * 64 + kk);
      h2v pv; pv.x = (_Float16)v.x; pv.y = (_Float16)v.y;
      *(h2v*)&xt[0][kk >> 5][(((kk >> 3) & 3) * 16) + row][kk & 7] = pv;
    }
  }
  __syncthreads();

  const int kb_w = w >> 1;
  const int lanep = ((2 * w + (lo >> 3)) & 3) * 16 + hi * 4;  // + r
  const int jw = lo & 7;

  for (int j = 0; j <= T_STEPS; ++j) {
    const int p = j & 1;

    if (isL0) {
      if (j < T_STEPS) {
        // ---- layer 0, step j ----
        h8v h00 = *(const h8v*)&h0t[p][0][l][0];
        h8v h01 = *(const h8v*)&h0t[p][1][l][0];
        h8v h02 = *(const h8v*)&h0t[p][2][l][0];
        h8v h03 = *(const h8v*)&h0t[p][3][l][0];
        h8v ax0 = *(const h8v*)&xt[p][0][l][0];
        h8v ax1 = *(const h8v*)&xt[p][1][l][0];
        f4v acc[4];
#pragma unroll
        for (int t = 0; t < 4; ++t) {
          const h8v* wxp = wxl + ((8 * t + w) * 2) * 64 + l;
          h8v wx0 = wxp[0];
          h8v wx1 = wxp[64];
          f4v z = {br[t], br[t], br[t], br[t]};
          z = __builtin_amdgcn_mfma_f32_16x16x32_f16(ax0, wx0, z, 0, 0, 0);
          z = __builtin_amdgcn_mfma_f32_16x16x32_f16(ax1, wx1, z, 0, 0, 0);
          z = __builtin_amdgcn_mfma_f32_16x16x32_f16(h00, Wr[t][0], z, 0, 0, 0);
          z = __builtin_amdgcn_mfma_f32_16x16x32_f16(h01, Wr[t][1], z, 0, 0, 0);
          z = __builtin_amdgcn_mfma_f32_16x16x32_f16(h02, Wr[t][2], z, 0, 0, 0);
          z = __builtin_amdgcn_mfma_f32_16x16x32_f16(h03, Wr[t][3], z, 0, 0, 0);
          acc[t] = z;
        }
#pragma unroll
        for (int r = 0; r < 4; ++r) {
          float cn = sigf(acc[1][r]) * cst[r] + sigf(acc[0][r]) * tanh_(acc[2][r]);
          cst[r] = cn;
          float hv = sigf(acc[3][r]) * tanh_(cn);
          h0t[p ^ 1][kb_w][lanep + r][jw] = (_Float16)hv;
        }
        if (j + 1 < T_STEPS) {  // stage x(j+1) (all 512 L0 threads)
          int row = tid >> 5, kk = (tid & 31) << 1;
          float2 v = *(const float2*)(x + (((long)(g * 16 + row)) * T_STEPS + (j + 1)) * 64 + kk);
          h2v pv; pv.x = (_Float16)v.x; pv.y = (_Float16)v.y;
          *(h2v*)&xt[p ^ 1][kk >> 5][(((kk >> 3) & 3) * 16) + row][kk & 7] = pv;
        }
      }
    } else {
      if (j >= 1) {
        // ---- layer 1, step j-1 ----
        int zero = 0;
        asm volatile("" : "+v"(zero));  // defeat LICM: keep gw loads in-loop
        h8v h00 = *(const h8v*)&h0t[p][0][l][0];
        h8v h01 = *(const h8v*)&h0t[p][1][l][0];
        h8v h02 = *(const h8v*)&h0t[p][2][l][0];
        h8v h03 = *(const h8v*)&h0t[p][3][l][0];
        h8v f10 = *(const h8v*)&h1t[p][0][l][0];
        h8v f11 = *(const h8v*)&h1t[p][1][l][0];
        h8v f12 = *(const h8v*)&h1t[p][2][l][0];
        h8v f13 = *(const h8v*)&h1t[p][3][l][0];
        f4v acc[4];
#pragma unroll
        for (int t = 0; t < 4; ++t) {
          int n = 8 * t + w;
          h8v gw0 = PBv[(n * 8 + 6) * 64 + l + zero];  // Whh1 ks4=2 (L2 stream)
          h8v gw1 = PBv[(n * 8 + 7) * 64 + l + zero];  // Whh1 ks4=3
          const h8v* wlp = whl + (n * 2) * 64 + l;
          h8v wl0 = wlp[0];
          h8v wl1 = wlp[64];
          f4v z = {br[t], br[t], br[t], br[t]};
          z = __builtin_amdgcn_mfma_f32_16x16x32_f16(h00, Wr[t][0], z, 0, 0, 0);
          z = __builtin_amdgcn_mfma_f32_16x16x32_f16(h01, Wr[t][1], z, 0, 0, 0);
          z = __builtin_amdgcn_mfma_f32_16x16x32_f16(h02, Wr[t][2], z, 0, 0, 0);
          z = __builtin_amdgcn_mfma_f32_16x16x32_f16(h03, Wr[t][3], z, 0, 0, 0);
          z = __builtin_amdgcn_mfma_f32_16x16x32_f16(f10, wl0, z, 0, 0, 0);
          z = __builtin_amdgcn_mfma_f32_16x16x32_f16(f11, wl1, z, 0, 0, 0);
          z = __builtin_amdgcn_mfma_f32_16x16x32_f16(f12, gw0, z, 0, 0, 0);
          z = __builtin_amdgcn_mfma_f32_16x16x32_f16(f13, gw1, z, 0, 0, 0);
          acc[t] = z;
        }
#pragma unroll
        for (int r = 0; r < 4; ++r) {
          float cn = sigf(acc[1][r]) * cst[r] + sigf(acc[0][r]) * tanh_(acc[2][r]);
          cst[r] = cn;
          float hv = sigf(acc[3][r]) * tanh_(cn);
          h1t[p ^ 1][kb_w][lanep + r][jw] = (_Float16)hv;
        }
      }
    }
    __syncthreads();
  }

  // ---- output projection: y = h1(T-1) . Wout^T + bout ; h1(T-1) in h1t[1] ----
  if (tid < 16) {
    float acc = bout[0];
#pragma unroll 4
    for (int u = 0; u < 128; ++u) {
      float hval = (float)h1t[1][u >> 5][(((u >> 3) & 3) * 16) + tid][u & 7];
      acc = fmaf(hval, Wout[u], acc);
    }
    out[g * 16 + tid] = acc;
  }
}

}  // namespace

extern "C" void kernel_launch(void* const* d_in, const int* in_sizes, int n_in,
                              void* d_out, int out_size, void* d_ws, size_t ws_size,
                              hipStream_t stream) {
  const float* x    = (const float*)d_in[0];
  const float* Wih0 = (const float*)d_in[1];
  const float* Whh0 = (const float*)d_in[2];
  const float* b0   = (const float*)d_in[3];
  const float* Wih1 = (const float*)d_in[4];
  const float* Whh1 = (const float*)d_in[5];
  const float* b1   = (const float*)d_in[6];
  const float* Wout = (const float*)d_in[7];
  const float* bout = (const float*)d_in[8];
  float* out = (float*)d_out;

  char* ws = (char*)d_ws;
  _Float16* PA = (_Float16*)ws;             // 196608 B
  _Float16* PB = (_Float16*)(ws + 196608);  // 262144 B

  const int lds_bytes = 65536 + 65536 + 8192 + 8192 + 4096;  // 151552
  hipFuncSetAttribute((const void*)lstm_block,
                      hipFuncAttributeMaxDynamicSharedMemorySize, lds_bytes);

  pack_w<<<dim3(896), dim3(256), 0, stream>>>(Wih0, Whh0, Wih1, Whh1, PA, PB);
  lstm_block<<<dim3(64), dim3(1024), lds_bytes, stream>>>(
      x, PA, PB, b0, b1, Wout, bout, out);
}